// Round 1
// baseline (282.904 us; speedup 1.0000x reference)
//
#include <hip/hip_runtime.h>
#include <hip/hip_bf16.h>
#include <math.h>

// Bidirectional cross-attention (B=8, L=2048, D=128, fp32 in/out).
//   E = X Y^T ; seq_hat = softmax_rows(E) @ Y   (done twice with X<->Y swap)
// Flash-style two-phase per block (stats, then apply), E in ~fp32 precision
// via bf16 hi/lo split (3 MFMA passes), PV in bf16.

#define LSEQ 2048
#define DIM  128
#define NBATCH 8
#define BM 128          // X rows per block
#define BJ 64           // j-tile
#define NJT (LSEQ / BJ) // 32
#define PADD (DIM + 8)  // 136 shorts per row (X/Y tiles)
#define PADJ (BJ + 8)   // 72 shorts per row (P / Vt tiles)

typedef short v8s __attribute__((ext_vector_type(8)));
typedef float v4f __attribute__((ext_vector_type(4)));

__device__ __forceinline__ short f2bf(float f) {
    union { float f; unsigned u; } v; v.f = f;
    unsigned r = (v.u + 0x7FFFu + ((v.u >> 16) & 1u)) >> 16;
    return (short)r;
}
__device__ __forceinline__ float bf2f(short s) {
    union { float f; unsigned u; } v;
    v.u = ((unsigned)(unsigned short)s) << 16;
    return v.f;
}

__global__ __launch_bounds__(256, 1)
void xattn_kernel(const float* __restrict__ S1, const float* __restrict__ S2,
                  float* __restrict__ out)
{
    __shared__ short Xh[BM][PADD];   // X tile hi (bf16 bits), row-major [i][d]
    __shared__ short Xl[BM][PADD];   // X tile lo
    __shared__ short Yh[BJ][PADD];   // Y tile hi, row-major [j][d]
    __shared__ short Yl[BJ][PADD];   // Y tile lo
    __shared__ short Pt[BM][PADJ];   // P = exp(E-m), [i][j] (A operand of PV)
    __shared__ short Vt[DIM][PADJ];  // Y tile hi transposed, [d][j] (B operand of PV)
    __shared__ float maxpart[2][BM];
    __shared__ float spart[2][BM];
    __shared__ float mnew[BM];
    __shared__ float runm[BM];
    __shared__ float runs[BM];
    __shared__ float invs[BM];

    const int tid  = threadIdx.x;
    const int lane = tid & 63;
    const int wave = tid >> 6;      // 0..3
    const int l15  = lane & 15;
    const int lg   = lane >> 4;     // 0..3
    const int wj   = wave >> 1;     // 0..1
    const int wi   = wave & 1;      // 0..1

    const int side = blockIdx.z;    // 0: X=S1,Y=S2 -> seq_1_hat ; 1: swapped
    const int bb   = blockIdx.y;
    const int rt   = blockIdx.x;

    const float* X = side ? S2 : S1;
    const float* Y = side ? S1 : S2;
    float* O = out + (size_t)side * (size_t)NBATCH * LSEQ * DIM;

    const float* Xg = X + ((size_t)bb * LSEQ + (size_t)rt * BM) * DIM;
    const float* Yg = Y + (size_t)bb * LSEQ * DIM;

    // ---- stage X tile once, hi/lo split ----
    #pragma unroll
    for (int it = 0; it < (BM * DIM / 4) / 256; ++it) {   // 16
        int idx = tid + it * 256;
        int r = idx >> 5;            // 0..127
        int c = (idx & 31) * 4;      // 0..124
        float4 v = *(const float4*)(Xg + (size_t)r * DIM + c);
        short h0 = f2bf(v.x), h1 = f2bf(v.y), h2 = f2bf(v.z), h3 = f2bf(v.w);
        short q0 = f2bf(v.x - bf2f(h0)), q1 = f2bf(v.y - bf2f(h1));
        short q2 = f2bf(v.z - bf2f(h2)), q3 = f2bf(v.w - bf2f(h3));
        *(short4*)&Xh[r][c] = make_short4(h0, h1, h2, h3);
        *(short4*)&Xl[r][c] = make_short4(q0, q1, q2, q3);
    }
    if (tid < BM) { runm[tid] = -INFINITY; runs[tid] = 0.f; }

    // ================= phase 1: row stats (m, s) =================
    for (int jt = 0; jt < NJT; ++jt) {
        __syncthreads();   // protect Yh/Yl reuse (and X/stats init on iter 0)
        #pragma unroll
        for (int it = 0; it < (BJ * DIM / 4) / 256; ++it) {  // 8
            int idx = tid + it * 256;
            int r = idx >> 5;            // 0..63
            int c = (idx & 31) * 4;
            float4 v = *(const float4*)(Yg + (size_t)(jt * BJ + r) * DIM + c);
            short h0 = f2bf(v.x), h1 = f2bf(v.y), h2 = f2bf(v.z), h3 = f2bf(v.w);
            short q0 = f2bf(v.x - bf2f(h0)), q1 = f2bf(v.y - bf2f(h1));
            short q2 = f2bf(v.z - bf2f(h2)), q3 = f2bf(v.w - bf2f(h3));
            *(short4*)&Yh[r][c] = make_short4(h0, h1, h2, h3);
            *(short4*)&Yl[r][c] = make_short4(q0, q1, q2, q3);
        }
        __syncthreads();

        // E^T tile = Y X^T : wave covers j in [wj*32,+32), i in [wi*64,+64)
        v4f e[2][4];
        #pragma unroll
        for (int fj = 0; fj < 2; ++fj)
            #pragma unroll
            for (int fi = 0; fi < 4; ++fi)
                e[fj][fi] = (v4f){0.f, 0.f, 0.f, 0.f};
        #pragma unroll
        for (int ks = 0; ks < 4; ++ks) {
            const int k0 = ks * 32 + lg * 8;
            v8s yh[2], yl2[2], xh[4], xl2[4];
            #pragma unroll
            for (int fj = 0; fj < 2; ++fj) {
                int jr = wj * 32 + fj * 16 + l15;
                yh[fj]  = *(const v8s*)&Yh[jr][k0];
                yl2[fj] = *(const v8s*)&Yl[jr][k0];
            }
            #pragma unroll
            for (int fi = 0; fi < 4; ++fi) {
                int ir = wi * 64 + fi * 16 + l15;
                xh[fi]  = *(const v8s*)&Xh[ir][k0];
                xl2[fi] = *(const v8s*)&Xl[ir][k0];
            }
            #pragma unroll
            for (int fj = 0; fj < 2; ++fj)
                #pragma unroll
                for (int fi = 0; fi < 4; ++fi) {
                    e[fj][fi] = __builtin_amdgcn_mfma_f32_16x16x32_bf16(yh[fj],  xh[fi],  e[fj][fi], 0, 0, 0);
                    e[fj][fi] = __builtin_amdgcn_mfma_f32_16x16x32_bf16(yh[fj],  xl2[fi], e[fj][fi], 0, 0, 0);
                    e[fj][fi] = __builtin_amdgcn_mfma_f32_16x16x32_bf16(yl2[fj], xh[fi],  e[fj][fi], 0, 0, 0);
                }
        }

        // per-column-i max over this tile's j (regs+fj local, then lanes lg)
        #pragma unroll
        for (int fi = 0; fi < 4; ++fi) {
            float m = -INFINITY;
            #pragma unroll
            for (int fj = 0; fj < 2; ++fj)
                #pragma unroll
                for (int rg = 0; rg < 4; ++rg)
                    m = fmaxf(m, e[fj][fi][rg]);
            m = fmaxf(m, __shfl_xor(m, 16));
            m = fmaxf(m, __shfl_xor(m, 32));
            if (lg == 0) maxpart[wj][wi * 64 + fi * 16 + l15] = m;
        }
        __syncthreads();
        if (tid < BM)
            mnew[tid] = fmaxf(runm[tid], fmaxf(maxpart[0][tid], maxpart[1][tid]));
        __syncthreads();
        #pragma unroll
        for (int fi = 0; fi < 4; ++fi) {
            const int ic = wi * 64 + fi * 16 + l15;
            const float m = mnew[ic];
            float s = 0.f;
            #pragma unroll
            for (int fj = 0; fj < 2; ++fj)
                #pragma unroll
                for (int rg = 0; rg < 4; ++rg)
                    s += __expf(e[fj][fi][rg] - m);
            s += __shfl_xor(s, 16);
            s += __shfl_xor(s, 32);
            if (lg == 0) spart[wj][ic] = s;
        }
        __syncthreads();
        if (tid < BM) {
            float mn = mnew[tid];
            runs[tid] = runs[tid] * __expf(runm[tid] - mn) + spart[0][tid] + spart[1][tid];
            runm[tid] = mn;
        }
    }
    __syncthreads();
    if (tid < BM) invs[tid] = 1.0f / runs[tid];

    // ================= phase 2: apply (O = P @ Y / s) =================
    v4f acc[4][4];
    #pragma unroll
    for (int fm = 0; fm < 4; ++fm)
        #pragma unroll
        for (int fd = 0; fd < 4; ++fd)
            acc[fm][fd] = (v4f){0.f, 0.f, 0.f, 0.f};

    for (int jt = 0; jt < NJT; ++jt) {
        __syncthreads();   // protect Yh/Yl/Vt reuse vs previous PV reads
        #pragma unroll
        for (int it = 0; it < (BJ * DIM / 4) / 256; ++it) {  // 8
            int idx = tid + it * 256;
            int r = idx >> 5;
            int c = (idx & 31) * 4;
            float4 v = *(const float4*)(Yg + (size_t)(jt * BJ + r) * DIM + c);
            short h0 = f2bf(v.x), h1 = f2bf(v.y), h2 = f2bf(v.z), h3 = f2bf(v.w);
            short q0 = f2bf(v.x - bf2f(h0)), q1 = f2bf(v.y - bf2f(h1));
            short q2 = f2bf(v.z - bf2f(h2)), q3 = f2bf(v.w - bf2f(h3));
            *(short4*)&Yh[r][c] = make_short4(h0, h1, h2, h3);
            *(short4*)&Yl[r][c] = make_short4(q0, q1, q2, q3);
            Vt[c + 0][r] = h0; Vt[c + 1][r] = h1;
            Vt[c + 2][r] = h2; Vt[c + 3][r] = h3;
        }
        __syncthreads();

        // recompute E^T tile (identical bits to phase 1 => p <= 1)
        v4f e[2][4];
        #pragma unroll
        for (int fj = 0; fj < 2; ++fj)
            #pragma unroll
            for (int fi = 0; fi < 4; ++fi)
                e[fj][fi] = (v4f){0.f, 0.f, 0.f, 0.f};
        #pragma unroll
        for (int ks = 0; ks < 4; ++ks) {
            const int k0 = ks * 32 + lg * 8;
            v8s yh[2], yl2[2], xh[4], xl2[4];
            #pragma unroll
            for (int fj = 0; fj < 2; ++fj) {
                int jr = wj * 32 + fj * 16 + l15;
                yh[fj]  = *(const v8s*)&Yh[jr][k0];
                yl2[fj] = *(const v8s*)&Yl[jr][k0];
            }
            #pragma unroll
            for (int fi = 0; fi < 4; ++fi) {
                int ir = wi * 64 + fi * 16 + l15;
                xh[fi]  = *(const v8s*)&Xh[ir][k0];
                xl2[fi] = *(const v8s*)&Xl[ir][k0];
            }
            #pragma unroll
            for (int fj = 0; fj < 2; ++fj)
                #pragma unroll
                for (int fi = 0; fi < 4; ++fi) {
                    e[fj][fi] = __builtin_amdgcn_mfma_f32_16x16x32_bf16(yh[fj],  xh[fi],  e[fj][fi], 0, 0, 0);
                    e[fj][fi] = __builtin_amdgcn_mfma_f32_16x16x32_bf16(yh[fj],  xl2[fi], e[fj][fi], 0, 0, 0);
                    e[fj][fi] = __builtin_amdgcn_mfma_f32_16x16x32_bf16(yl2[fj], xh[fi],  e[fj][fi], 0, 0, 0);
                }
        }

        // P = exp(E - m) -> bf16, write transposed into Pt[i][j] (short4 rows)
        #pragma unroll
        for (int fi = 0; fi < 4; ++fi) {
            const int ic = wi * 64 + fi * 16 + l15;
            const float m = runm[ic];
            #pragma unroll
            for (int fj = 0; fj < 2; ++fj) {
                short p0 = f2bf(__expf(e[fj][fi][0] - m));
                short p1 = f2bf(__expf(e[fj][fi][1] - m));
                short p2 = f2bf(__expf(e[fj][fi][2] - m));
                short p3 = f2bf(__expf(e[fj][fi][3] - m));
                *(short4*)&Pt[ic][wj * 32 + fj * 16 + lg * 4] = make_short4(p0, p1, p2, p3);
            }
        }
        __syncthreads();

        // PV: acc[i][d] += P[i][j] * Y[j][d]  (A=Pt rows, B=Vt rows)
        #pragma unroll
        for (int ks = 0; ks < 2; ++ks) {
            const int k0 = ks * 32 + lg * 8;
            v8s pa[4], vb[4];
            #pragma unroll
            for (int fm = 0; fm < 4; ++fm)
                pa[fm] = *(const v8s*)&Pt[wj * 64 + fm * 16 + l15][k0];
            #pragma unroll
            for (int fd = 0; fd < 4; ++fd)
                vb[fd] = *(const v8s*)&Vt[wi * 64 + fd * 16 + l15][k0];
            #pragma unroll
            for (int fm = 0; fm < 4; ++fm)
                #pragma unroll
                for (int fd = 0; fd < 4; ++fd)
                    acc[fm][fd] = __builtin_amdgcn_mfma_f32_16x16x32_bf16(pa[fm], vb[fd], acc[fm][fd], 0, 0, 0);
        }
    }

    // finalize: divide by s, write out
    #pragma unroll
    for (int fm = 0; fm < 4; ++fm) {
        #pragma unroll
        for (int rg = 0; rg < 4; ++rg) {
            const int ir = wj * 64 + fm * 16 + lg * 4 + rg;
            const float inv = invs[ir];
            float* orow = O + ((size_t)bb * LSEQ + (size_t)rt * BM + ir) * DIM;
            #pragma unroll
            for (int fd = 0; fd < 4; ++fd)
                orow[wi * 64 + fd * 16 + l15] = acc[fm][fd][rg] * inv;
        }
    }
}

extern "C" void kernel_launch(void* const* d_in, const int* in_sizes, int n_in,
                              void* d_out, int out_size, void* d_ws, size_t ws_size,
                              hipStream_t stream) {
    const float* s1 = (const float*)d_in[0];
    const float* s2 = (const float*)d_in[1];
    float* out = (float*)d_out;
    dim3 grid(LSEQ / BM, NBATCH, 2);   // 16 x 8 x 2 = 256 blocks (1/CU)
    dim3 block(256);
    xattn_kernel<<<grid, block, 0, stream>>>(s1, s2, out);
}

// Round 2
// 115.891 us; speedup vs baseline: 2.4411x; 2.4411x over previous
//
#include <hip/hip_runtime.h>
#include <hip/hip_bf16.h>
#include <math.h>

// Bidirectional cross-attention (B=8, L=2048, D=128, fp32 in/out).
// One-pass flash with online softmax (defer-max THR=8), E in ~fp32 via
// bf16 hi/lo split (3 MFMA passes), PV in bf16. X frags live in registers.
// 512 threads (8 waves), XCD-grouped block swizzle for Y L2 sharing.

#define LSEQ 2048
#define DIM  128
#define NBATCH 8
#define BM 128          // X rows per block
#define BJ 64           // j-tile
#define NJT (LSEQ / BJ) // 32
#define PADD (DIM + 8)  // 136 shorts per row (Y tiles)
#define PADJ (BJ + 8)   // 72 shorts per row (Pt)
#define VROW 72         // Vt row in shorts (9 chunks of 8; chunk-XOR swizzled)
#define THR_DEFER 8.0f

typedef short v8s __attribute__((ext_vector_type(8)));
typedef float v4f __attribute__((ext_vector_type(4)));

// Vt element (d, j) -> short index. Chunk (8 j's) XOR-swizzled by d bits so
// scatter writes (32 lanes same j, d=4l+q) spread across ~8 banks instead of 2.
#define VT_IDX(d, j) ((d)*VROW + (((((j) >> 3) ^ (((d) >> 2) & 7))) << 3) + ((j) & 7))

__device__ __forceinline__ short f2bf(float f) {
    union { float f; unsigned u; } v; v.f = f;
    unsigned r = (v.u + 0x7FFFu + ((v.u >> 16) & 1u)) >> 16;
    return (short)r;
}
__device__ __forceinline__ float bf2f(short s) {
    union { float f; unsigned u; } v;
    v.u = ((unsigned)(unsigned short)s) << 16;
    return v.f;
}

__global__ __launch_bounds__(512, 2)
void xattn_kernel(const float* __restrict__ S1, const float* __restrict__ S2,
                  float* __restrict__ out)
{
    __shared__ short Yh[BJ][PADD];   // Y tile hi (bf16 bits), [j][d]
    __shared__ short Yl[BJ][PADD];   // Y tile lo
    __shared__ short Pt[BM][PADJ];   // P = exp(E-m), [i][j]
    __shared__ short Vt[DIM * VROW]; // Y hi transposed [d][j], chunk-swizzled
    __shared__ float maxpart[2][BM];
    __shared__ float spart[2][BM];
    __shared__ float runm[BM];
    __shared__ float runs[BM];
    __shared__ float fac[BM];        // per-tile rescale factor; reused as 1/s at end

    const int tid  = threadIdx.x;
    const int lane = tid & 63;
    const int wave = tid >> 6;      // 0..7
    const int l15  = lane & 15;
    const int lg   = lane >> 4;     // 0..3
    const int wj   = wave >> 2;     // E grid: j-half (0..1)
    const int wi   = wave & 3;      //         i-quarter (0..3)
    const int wi2  = wave >> 1;     // PV grid: i-quarter (0..3)
    const int wd   = wave & 1;      //          d-half (0..1)

    // XCD-grouped decode: blocks sharing one (batch, side) Y-stream land on
    // one XCD (assumes round-robin bx%8 -> XCD; perf-only assumption).
    const int bx   = blockIdx.x;
    const int xcd  = bx & 7;
    const int slot = bx >> 3;              // 0..31
    const int g    = xcd * 2 + (slot >> 4); // 0..15 = (side, batch) group
    const int rt   = slot & 15;            // row-tile
    const int side = g >> 3;
    const int bb   = g & 7;

    const float* X = side ? S2 : S1;
    const float* Y = side ? S1 : S2;
    float* O = out + (size_t)side * (size_t)NBATCH * LSEQ * DIM;
    const float* Xg = X + ((size_t)bb * LSEQ + (size_t)rt * BM) * DIM;
    const float* Yg = Y + (size_t)bb * LSEQ * DIM;

    // ---- X fragments -> registers (loop-invariant), hi/lo split ----
    v8s xh[2][4], xl[2][4];
    #pragma unroll
    for (int fi = 0; fi < 2; ++fi) {
        const int row = wi * 32 + fi * 16 + l15;
        #pragma unroll
        for (int ks = 0; ks < 4; ++ks) {
            const int col = ks * 32 + lg * 8;
            float4 a = *(const float4*)(Xg + (size_t)row * DIM + col);
            float4 b = *(const float4*)(Xg + (size_t)row * DIM + col + 4);
            v8s h, l;
            short t;
            t = f2bf(a.x); h[0] = t; l[0] = f2bf(a.x - bf2f(t));
            t = f2bf(a.y); h[1] = t; l[1] = f2bf(a.y - bf2f(t));
            t = f2bf(a.z); h[2] = t; l[2] = f2bf(a.z - bf2f(t));
            t = f2bf(a.w); h[3] = t; l[3] = f2bf(a.w - bf2f(t));
            t = f2bf(b.x); h[4] = t; l[4] = f2bf(b.x - bf2f(t));
            t = f2bf(b.y); h[5] = t; l[5] = f2bf(b.y - bf2f(t));
            t = f2bf(b.z); h[6] = t; l[6] = f2bf(b.z - bf2f(t));
            t = f2bf(b.w); h[7] = t; l[7] = f2bf(b.w - bf2f(t));
            xh[fi][ks] = h; xl[fi][ks] = l;
        }
    }

    if (tid < BM) { runm[tid] = -INFINITY; runs[tid] = 0.f; }

    // staging index precompute (4 float4 per thread per tile)
    int rI[4], cI[4];
    #pragma unroll
    for (int it = 0; it < 4; ++it) {
        int idx = tid + it * 512;
        rI[it] = idx >> 5;          // 0..63
        cI[it] = (idx & 31) * 4;    // 0..124
    }
    // prefetch tile 0
    float4 pre[4];
    #pragma unroll
    for (int it = 0; it < 4; ++it)
        pre[it] = *(const float4*)(Yg + (size_t)rI[it] * DIM + cI[it]);

    v4f acc[2][4];
    #pragma unroll
    for (int fm = 0; fm < 2; ++fm)
        #pragma unroll
        for (int fd = 0; fd < 4; ++fd)
            acc[fm][fd] = (v4f){0.f, 0.f, 0.f, 0.f};

    for (int jt = 0; jt < NJT; ++jt) {
        __syncthreads();   // A: prev PV reads done; LDS free
        #pragma unroll
        for (int it = 0; it < 4; ++it) {
            float4 v = pre[it];
            const int r = rI[it], c = cI[it];
            short h0 = f2bf(v.x), h1 = f2bf(v.y), h2 = f2bf(v.z), h3 = f2bf(v.w);
            short q0 = f2bf(v.x - bf2f(h0)), q1 = f2bf(v.y - bf2f(h1));
            short q2 = f2bf(v.z - bf2f(h2)), q3 = f2bf(v.w - bf2f(h3));
            *(short4*)&Yh[r][c] = make_short4(h0, h1, h2, h3);
            *(short4*)&Yl[r][c] = make_short4(q0, q1, q2, q3);
            Vt[VT_IDX(c + 0, r)] = h0;
            Vt[VT_IDX(c + 1, r)] = h1;
            Vt[VT_IDX(c + 2, r)] = h2;
            Vt[VT_IDX(c + 3, r)] = h3;
        }
        // issue next tile's loads; they fly during E/stats/PV
        if (jt + 1 < NJT) {
            #pragma unroll
            for (int it = 0; it < 4; ++it)
                pre[it] = *(const float4*)(Yg + (size_t)((jt + 1) * BJ + rI[it]) * DIM + cI[it]);
        }
        __syncthreads();   // B: Y tile ready

        // ---- E^T tile = Y X^T (wave: j 32 x i 32), 3-pass split ----
        v4f e[2][2];
        #pragma unroll
        for (int fj = 0; fj < 2; ++fj)
            #pragma unroll
            for (int fi = 0; fi < 2; ++fi)
                e[fj][fi] = (v4f){0.f, 0.f, 0.f, 0.f};
        #pragma unroll
        for (int ks = 0; ks < 4; ++ks) {
            const int k0 = ks * 32 + lg * 8;
            v8s yh2[2], yl2[2];
            #pragma unroll
            for (int fj = 0; fj < 2; ++fj) {
                const int jr = wj * 32 + fj * 16 + l15;
                yh2[fj] = *(const v8s*)&Yh[jr][k0];
                yl2[fj] = *(const v8s*)&Yl[jr][k0];
            }
            #pragma unroll
            for (int fj = 0; fj < 2; ++fj)
                #pragma unroll
                for (int fi = 0; fi < 2; ++fi) {
                    e[fj][fi] = __builtin_amdgcn_mfma_f32_16x16x32_bf16(yh2[fj], xh[fi][ks], e[fj][fi], 0, 0, 0);
                    e[fj][fi] = __builtin_amdgcn_mfma_f32_16x16x32_bf16(yh2[fj], xl[fi][ks], e[fj][fi], 0, 0, 0);
                    e[fj][fi] = __builtin_amdgcn_mfma_f32_16x16x32_bf16(yl2[fj], xh[fi][ks], e[fj][fi], 0, 0, 0);
                }
        }

        // ---- tile max per row i (reduce over j: regs then lg lanes) ----
        #pragma unroll
        for (int fi = 0; fi < 2; ++fi) {
            float m = -INFINITY;
            #pragma unroll
            for (int fj = 0; fj < 2; ++fj)
                #pragma unroll
                for (int rg = 0; rg < 4; ++rg)
                    m = fmaxf(m, e[fj][fi][rg]);
            m = fmaxf(m, __shfl_xor(m, 16));
            m = fmaxf(m, __shfl_xor(m, 32));
            if (lg == 0) maxpart[wj][wi * 32 + fi * 16 + l15] = m;
        }
        __syncthreads();   // C

        // ---- stats: fold prev spart, defer-max update ----
        if (tid < BM) {
            float rs = runs[tid];
            if (jt > 0) rs += spart[0][tid] + spart[1][tid];
            float mt = fmaxf(maxpart[0][tid], maxpart[1][tid]);
            float mo = runm[tid];
            float f = 1.0f;
            if (mt > mo + THR_DEFER) { f = __expf(mo - mt); runm[tid] = mt; rs *= f; }
            fac[tid] = f;
            runs[tid] = rs;
        }
        __syncthreads();   // D

        // ---- acc rescale (rare after first tiles) ----
        {
            float fr[2][4];
            bool need = false;
            #pragma unroll
            for (int fm = 0; fm < 2; ++fm)
                #pragma unroll
                for (int rg = 0; rg < 4; ++rg) {
                    fr[fm][rg] = fac[wi2 * 32 + fm * 16 + lg * 4 + rg];
                    need = need || (fr[fm][rg] != 1.0f);
                }
            if (__any(need)) {
                #pragma unroll
                for (int fm = 0; fm < 2; ++fm)
                    #pragma unroll
                    for (int fd = 0; fd < 4; ++fd)
                        #pragma unroll
                        for (int rg = 0; rg < 4; ++rg)
                            acc[fm][fd][rg] *= fr[fm][rg];
            }
        }

        // ---- P = exp(E-m) -> Pt (bf16), s-partials ----
        #pragma unroll
        for (int fi = 0; fi < 2; ++fi) {
            const int ic = wi * 32 + fi * 16 + l15;
            const float m = runm[ic];
            float s = 0.f;
            #pragma unroll
            for (int fj = 0; fj < 2; ++fj) {
                float p0 = __expf(e[fj][fi][0] - m);
                float p1 = __expf(e[fj][fi][1] - m);
                float p2 = __expf(e[fj][fi][2] - m);
                float p3 = __expf(e[fj][fi][3] - m);
                s += p0 + p1 + p2 + p3;
                *(short4*)&Pt[ic][wj * 32 + fj * 16 + lg * 4] =
                    make_short4(f2bf(p0), f2bf(p1), f2bf(p2), f2bf(p3));
            }
            s += __shfl_xor(s, 16);
            s += __shfl_xor(s, 32);
            if (lg == 0) spart[wj][ic] = s;
        }
        __syncthreads();   // E: Pt ready

        // ---- PV: acc[i][d] += P[i][j] * Y[j][d] ----
        #pragma unroll
        for (int ks = 0; ks < 2; ++ks) {
            const int k0 = ks * 32 + lg * 8;
            v8s pa[2], vb[4];
            #pragma unroll
            for (int fm = 0; fm < 2; ++fm)
                pa[fm] = *(const v8s*)&Pt[wi2 * 32 + fm * 16 + l15][k0];
            #pragma unroll
            for (int fd = 0; fd < 4; ++fd) {
                const int d = wd * 64 + fd * 16 + l15;
                vb[fd] = *(const v8s*)&Vt[VT_IDX(d, k0)];
            }
            #pragma unroll
            for (int fm = 0; fm < 2; ++fm)
                #pragma unroll
                for (int fd = 0; fd < 4; ++fd)
                    acc[fm][fd] = __builtin_amdgcn_mfma_f32_16x16x32_bf16(pa[fm], vb[fd], acc[fm][fd], 0, 0, 0);
        }
    }

    // ---- finalize: fold last spart, invert, write out ----
    __syncthreads();
    if (tid < BM) {
        float rs = runs[tid] + spart[0][tid] + spart[1][tid];
        fac[tid] = 1.0f / rs;
    }
    __syncthreads();

    #pragma unroll
    for (int fm = 0; fm < 2; ++fm)
        #pragma unroll
        for (int rg = 0; rg < 4; ++rg) {
            const int ir = wi2 * 32 + fm * 16 + lg * 4 + rg;
            const float inv = fac[ir];
            float* orow = O + ((size_t)bb * LSEQ + (size_t)rt * BM + ir) * DIM;
            #pragma unroll
            for (int fd = 0; fd < 4; ++fd)
                orow[wd * 64 + fd * 16 + l15] = acc[fm][fd][rg] * inv;
        }
}

extern "C" void kernel_launch(void* const* d_in, const int* in_sizes, int n_in,
                              void* d_out, int out_size, void* d_ws, size_t ws_size,
                              hipStream_t stream) {
    const float* s1 = (const float*)d_in[0];
    const float* s2 = (const float*)d_in[1];
    float* out = (float*)d_out;
    dim3 grid(256, 1, 1);   // flat; XCD-grouped decode in-kernel
    dim3 block(512);
    xattn_kernel<<<grid, block, 0, stream>>>(s1, s2, out);
}